// Round 5
// baseline (867.490 us; speedup 1.0000x reference)
//
#include <hip/hip_runtime.h>
#include <stdint.h>

#define NNODES 50000
#define NREL 4
#define NEDGES 250000
#define INF 512
#define HIDF 512
#define OUTF 256
#define KCAT 2560   // 5 * 512
#define SCANB 49    // ceil(50000/1024)

typedef unsigned short u16;
typedef u16 u16x8 __attribute__((ext_vector_type(8)));
typedef __bf16 bf16x8 __attribute__((ext_vector_type(8)));
typedef float f32x4 __attribute__((ext_vector_type(4)));

__device__ __forceinline__ float bf2f(u16 b) {
    unsigned u = ((unsigned)b) << 16;
    return __builtin_bit_cast(float, u);
}
__device__ __forceinline__ u16 f2bf(float f) {
    unsigned u = __builtin_bit_cast(unsigned, f);
    u = (u + 0x7fffu + ((u >> 16) & 1u)) >> 16;
    return (u16)u;
}

#define GLOAD_LDS16(gsrc, ldst)                                                  \
    __builtin_amdgcn_global_load_lds(                                            \
        (__attribute__((address_space(1))) void*)(gsrc),                         \
        (__attribute__((address_space(3))) void*)(ldst), 16, 0, 0)

// ---------------- setup kernels ----------------

__global__ void cast_bf16_kernel(const float* __restrict__ in, u16* __restrict__ out, long total) {
    long i = ((long)blockIdx.x * blockDim.x + threadIdx.x) * 8;
    long stride = (long)gridDim.x * blockDim.x * 8;
    for (; i + 7 < total; i += stride) {
        float4 v0 = *(const float4*)(in + i);
        float4 v1 = *(const float4*)(in + i + 4);
        u16x8 o;
        o[0] = f2bf(v0.x); o[1] = f2bf(v0.y); o[2] = f2bf(v0.z); o[3] = f2bf(v0.w);
        o[4] = f2bf(v1.x); o[5] = f2bf(v1.y); o[6] = f2bf(v1.z); o[7] = f2bf(v1.w);
        *(u16x8*)(out + i) = o;
    }
}

// Fused weight/bias prep.
// WT[n][s*512 + k]; s=0 -> sum_r Wself[r][k][n]; s=1..4 -> Wneigh[s-1][k][n]
__global__ void prep_weights_kernel(const float* __restrict__ Ws1, const float* __restrict__ Wn1,
                                    const float* __restrict__ Ws2, const float* __restrict__ Wn2,
                                    const float* __restrict__ b1, const float* __restrict__ b2,
                                    u16* __restrict__ WT1, u16* __restrict__ WT2,
                                    float* __restrict__ b1s, float* __restrict__ b2s) {
    const int T1 = HIDF * KCAT;
    const int T2 = OUTF * KCAT;
    const int total = T1 + T2 + HIDF + OUTF;
    for (int idx = blockIdx.x * blockDim.x + threadIdx.x; idx < total;
         idx += gridDim.x * blockDim.x) {
        if (idx < T1 + T2) {
            const float* Wself;
            const float* Wneigh;
            u16* WT;
            int N, id;
            if (idx < T1) { Wself = Ws1; Wneigh = Wn1; WT = WT1; N = HIDF; id = idx; }
            else          { Wself = Ws2; Wneigh = Wn2; WT = WT2; N = OUTF; id = idx - T1; }
            int n = id / KCAT;
            int kg = id - n * KCAT;
            int s = kg >> 9;
            int k = kg & 511;
            float v;
            if (s == 0) {
                v = Wself[(size_t)k * N + n] + Wself[(size_t)(512 + k) * N + n] +
                    Wself[(size_t)(1024 + k) * N + n] + Wself[(size_t)(1536 + k) * N + n];
            } else {
                v = Wneigh[((size_t)(s - 1) * 512 + k) * N + n];
            }
            WT[id] = f2bf(v);
        } else if (idx < T1 + T2 + HIDF) {
            int t = idx - T1 - T2;
            b1s[t] = b1[t] + b1[HIDF + t] + b1[2 * HIDF + t] + b1[3 * HIDF + t];
        } else {
            int t = idx - T1 - T2 - HIDF;
            b2s[t] = b2[t] + b2[OUTF + t] + b2[2 * OUTF + t] + b2[3 * OUTF + t];
        }
    }
}

// ---------------- CSR build ----------------

__global__ void hist_kernel(const int* __restrict__ dst, int* __restrict__ deg) {
    int r = blockIdx.y;
    int i = blockIdx.x * blockDim.x + threadIdx.x;
    if (i < NEDGES) atomicAdd(&deg[r * NNODES + dst[r * NEDGES + i]], 1);
}

// 3-kernel scan: per-block exclusive scan + block sums -> scan block sums -> add offsets
__global__ __launch_bounds__(1024) void scan1_kernel(const int* __restrict__ deg,
                                                     int* __restrict__ rp, int* __restrict__ bsum) {
    int rel = blockIdx.x / SCANB, blk = blockIdx.x % SCANB;
    int i = blk * 1024 + threadIdx.x;
    int v = (i < NNODES) ? deg[rel * NNODES + i] : 0;
    __shared__ int wsum[16];
    int lane = threadIdx.x & 63, wid = threadIdx.x >> 6;
    int x = v;
#pragma unroll
    for (int off = 1; off < 64; off <<= 1) {
        int o = __shfl_up(x, off);
        if (lane >= off) x += o;
    }
    if (lane == 63) wsum[wid] = x;
    __syncthreads();
    if (wid == 0) {
        int s = (lane < 16) ? wsum[lane] : 0;
#pragma unroll
        for (int off = 1; off < 16; off <<= 1) {
            int o = __shfl_up(s, off);
            if (lane >= off) s += o;
        }
        if (lane < 16) wsum[lane] = s;
    }
    __syncthreads();
    int excl = (wid > 0 ? wsum[wid - 1] : 0) + x - v;
    if (i < NNODES) rp[rel * (NNODES + 1) + i] = excl;
    if (threadIdx.x == 1023) bsum[blockIdx.x] = excl + v;
}

__global__ void scan2_kernel(const int* __restrict__ bsum, int* __restrict__ bofs) {
    int r = threadIdx.x >> 6, lane = threadIdx.x & 63;  // 4 waves, one per rel
    int v = (lane < SCANB) ? bsum[r * SCANB + lane] : 0;
    int x = v;
#pragma unroll
    for (int off = 1; off < 64; off <<= 1) {
        int o = __shfl_up(x, off);
        if (lane >= off) x += o;
    }
    if (lane < SCANB) bofs[r * SCANB + lane] = x - v;
}

__global__ __launch_bounds__(1024) void scan3_kernel(int* __restrict__ rp, int* __restrict__ cur,
                                                     const int* __restrict__ bofs) {
    int rel = blockIdx.x / SCANB, blk = blockIdx.x % SCANB;
    int i = blk * 1024 + threadIdx.x;
    if (i < NNODES) {
        int v = rp[rel * (NNODES + 1) + i] + bofs[rel * SCANB + blk];
        rp[rel * (NNODES + 1) + i] = v;
        cur[rel * NNODES + i] = v;
        if (i == 0) rp[rel * (NNODES + 1) + NNODES] = NEDGES;
    }
}

__global__ void fill_kernel(const int* __restrict__ esrc, const int* __restrict__ edst,
                            int* __restrict__ cur, int* __restrict__ col) {
    int r = blockIdx.y;
    int i = blockIdx.x * blockDim.x + threadIdx.x;
    if (i < NEDGES) {
        int d = edst[r * NEDGES + i];
        int pos = atomicAdd(&cur[r * NNODES + d], 1);
        col[r * NEDGES + pos] = esrc[r * NEDGES + i];
    }
}

// ---------------- aggregation: one wave per (node, rel) ----------------
// out[rel][node][f] = (sum_{e in CSR_rel[node]} src[col[e]][f]) / max(deg,1), bf16
// Latency fix: one coalesced load grabs up to 64 neighbor indices for the wave
// (cl[p0+lane]); readlane broadcasts each -> row-gather addresses have NO load
// dependency, and 4 independent 1KB row loads are kept in flight per iteration.

__global__ __launch_bounds__(256) void aggregate_kernel(const u16* __restrict__ src,
                                                        const int* __restrict__ rp,
                                                        const int* __restrict__ col,
                                                        u16* __restrict__ out) {
    int node = blockIdx.x * 4 + (threadIdx.x >> 6);
    int rel = blockIdx.y;
    if (node >= NNODES) return;
    const int* r = rp + rel * (NNODES + 1);
    const int* cl = col + rel * NEDGES;
    int l = threadIdx.x & 63;
    int p0 = r[node], p1 = r[node + 1];
    int d = p1 - p0;
    float scale = (d > 0) ? 1.0f / (float)d : 1.0f;
    float acc[8] = {0.f, 0.f, 0.f, 0.f, 0.f, 0.f, 0.f, 0.f};
    const u16* srcl = src + l * 8;
    for (int base = 0; base < d; base += 64) {
        int ci = p0 + base + l;
        int myc = cl[ci < p1 ? ci : (p1 - 1)];   // coalesced index block for this wave
        int lim = d - base;
        if (lim > 64) lim = 64;
        int e = 0;
        for (; e + 4 <= lim; e += 4) {
            int s0 = __builtin_amdgcn_readlane(myc, e);
            int s1 = __builtin_amdgcn_readlane(myc, e + 1);
            int s2 = __builtin_amdgcn_readlane(myc, e + 2);
            int s3 = __builtin_amdgcn_readlane(myc, e + 3);
            u16x8 v0 = *(const u16x8*)(srcl + (size_t)s0 * 512);
            u16x8 v1 = *(const u16x8*)(srcl + (size_t)s1 * 512);
            u16x8 v2 = *(const u16x8*)(srcl + (size_t)s2 * 512);
            u16x8 v3 = *(const u16x8*)(srcl + (size_t)s3 * 512);
#pragma unroll
            for (int j = 0; j < 8; ++j)
                acc[j] += (bf2f(v0[j]) + bf2f(v1[j])) + (bf2f(v2[j]) + bf2f(v3[j]));
        }
        for (; e < lim; ++e) {
            int s0 = __builtin_amdgcn_readlane(myc, e);
            u16x8 v0 = *(const u16x8*)(srcl + (size_t)s0 * 512);
#pragma unroll
            for (int j = 0; j < 8; ++j) acc[j] += bf2f(v0[j]);
        }
    }
    u16x8 o;
#pragma unroll
    for (int j = 0; j < 8; ++j) o[j] = f2bf(acc[j] * scale);
    *(u16x8*)(out + ((size_t)rel * NNODES + node) * 512 + l * 8) = o;
}

// ---------------- GEMM: C[M][N] = concat_K(A0..A4) @ WT^T + bias ----------------
// A_s: [M][512] bf16 row-major.  WT: [N][2560] bf16 row-major (pre-transposed weights).
// OUTMODE 0: out = bf16(relu(acc+bias));  OUTMODE 1: out = f32(acc+bias)
// Grid: dim3(N/128, nrowblk). Block id is remapped (bijective XCD chunking, m204) so the
// ncol column-blocks sharing one A row-panel dispatch adjacently AND on the same XCD ->
// A panel fetched from HBM once, reused via L2.

template <int N, int OUTMODE>
__global__ __launch_bounds__(256, 4) void gemm_kernel(
    const u16* __restrict__ A0, const u16* __restrict__ A1, const u16* __restrict__ A2,
    const u16* __restrict__ A3, const u16* __restrict__ A4, const u16* __restrict__ WT,
    const float* __restrict__ bias, void* __restrict__ outp, int M) {
    __shared__ u16 ldsA[128 * 64];
    __shared__ u16 ldsB[128 * 64];
    const int t = threadIdx.x;
    const int w = t >> 6, l = t & 63;
    const int wr = w >> 1, wc = w & 1;

    constexpr int ncol = N >> 7;
    const int nwg = gridDim.x * gridDim.y;
    const int orig = blockIdx.y * gridDim.x + blockIdx.x;  // hardware dispatch order
    const int q = nwg >> 3, rr = nwg & 7, xcd = orig & 7, loc = orig >> 3;
    const int v = (xcd < rr) ? xcd * (q + 1) + loc : rr * (q + 1) + (xcd - rr) * q + loc;
    const int rowBase = (v / ncol) * 128;
    const int colBase = (v % ncol) * 128;

    f32x4 acc[4][4] = {};

    const u16* const As[5] = {A0, A1, A2, A3, A4};
    const int sr = t >> 3;       // 0..31 staging row within a call
    const int gp = t & 7;        // physical granule (16B)
    const int lr = l & 15, lg = l >> 4;

#pragma unroll
    for (int s = 0; s < 5; ++s) {
        const u16* __restrict__ Asrc = As[s];
        for (int ts = 0; ts < 8; ++ts) {
            const int klocal = ts * 64;
            const int kglob = s * 512 + klocal;
            // stage A tile (128 x 64 bf16), pre-swizzled source, linear LDS dest
#pragma unroll
            for (int c = 0; c < 4; ++c) {
                int r = c * 32 + sr;
                int gl = gp ^ (r & 7);
                int grow = rowBase + r;
                if (grow > M - 1) grow = M - 1;
                const u16* gsrc = Asrc + (size_t)grow * 512 + klocal + gl * 8;
                GLOAD_LDS16(gsrc, ldsA + (c * 2048 + w * 512));
            }
            // stage B tile (128 output-cols x 64 k)
#pragma unroll
            for (int c = 0; c < 4; ++c) {
                int r = c * 32 + sr;
                int gl = gp ^ (r & 7);
                const u16* gsrc = WT + (size_t)(colBase + r) * KCAT + kglob + gl * 8;
                GLOAD_LDS16(gsrc, ldsB + (c * 2048 + w * 512));
            }
            __syncthreads();   // drains vmcnt before any wave reads LDS
#pragma unroll
            for (int kh = 0; kh < 2; ++kh) {
                bf16x8 av[4], bv[4];
#pragma unroll
                for (int m = 0; m < 4; ++m) {
                    int r = wr * 64 + m * 16 + lr;
                    int g = (kh * 4 + lg) ^ (r & 7);
                    av[m] = *(const bf16x8*)((const char*)ldsA + r * 128 + g * 16);
                }
#pragma unroll
                for (int n = 0; n < 4; ++n) {
                    int r = wc * 64 + n * 16 + lr;
                    int g = (kh * 4 + lg) ^ (r & 7);
                    bv[n] = *(const bf16x8*)((const char*)ldsB + r * 128 + g * 16);
                }
#pragma unroll
                for (int m = 0; m < 4; ++m)
#pragma unroll
                    for (int n = 0; n < 4; ++n)
                        acc[m][n] =
                            __builtin_amdgcn_mfma_f32_16x16x32_bf16(av[m], bv[n], acc[m][n], 0, 0, 0);
            }
            __syncthreads();   // compute done before next stage overwrites
        }
    }

    const int lq = l >> 4;
#pragma unroll
    for (int m = 0; m < 4; ++m) {
#pragma unroll
        for (int n = 0; n < 4; ++n) {
#pragma unroll
            for (int j = 0; j < 4; ++j) {
                int row = rowBase + wr * 64 + m * 16 + lq * 4 + j;
                int colc = colBase + wc * 64 + n * 16 + lr;
                if (row < M) {
                    float vv = acc[m][n][j] + bias[colc];
                    if (OUTMODE == 0) {
                        vv = vv > 0.f ? vv : 0.f;
                        ((u16*)outp)[(size_t)row * N + colc] = f2bf(vv);
                    } else {
                        ((float*)outp)[(size_t)row * N + colc] = vv;
                    }
                }
            }
        }
    }
}

// ---------------- host ----------------

extern "C" void kernel_launch(void* const* d_in, const int* in_sizes, int n_in,
                              void* d_out, int out_size, void* d_ws, size_t ws_size,
                              hipStream_t stream) {
    const float* x = (const float*)d_in[0];
    const float* Wself1 = (const float*)d_in[1];
    const float* Wneigh1 = (const float*)d_in[2];
    const float* b1 = (const float*)d_in[3];
    const float* Wself2 = (const float*)d_in[4];
    const float* Wneigh2 = (const float*)d_in[5];
    const float* b2 = (const float*)d_in[6];
    const int* esrc = (const int*)d_in[7];
    const int* edst = (const int*)d_in[8];

    char* ws = (char*)d_ws;
    size_t off = 0;
    auto alloc = [&](size_t bytes) {
        char* p = ws + off;
        off += (bytes + 255) & ~(size_t)255;
        return p;
    };
    const size_t plane = (size_t)NNODES * 512;
    u16* xB = (u16*)alloc(plane * 2);             // x in bf16
    u16* mB = (u16*)alloc(NREL * plane * 2);      // 4 aggregate buffers
    u16* h1B = (u16*)alloc(plane * 2);            // relu(h1) in bf16
    u16* WT1 = (u16*)alloc((size_t)HIDF * KCAT * 2);
    u16* WT2 = (u16*)alloc((size_t)OUTF * KCAT * 2);
    float* b1s = (float*)alloc(HIDF * 4);
    float* b2s = (float*)alloc(OUTF * 4);
    int* deg = (int*)alloc((size_t)NREL * NNODES * 4);
    int* rp = (int*)alloc((size_t)NREL * (NNODES + 1) * 4);
    int* cur = (int*)alloc((size_t)NREL * NNODES * 4);
    int* col = (int*)alloc((size_t)NREL * NEDGES * 4);
    int* bsum = (int*)alloc((size_t)NREL * SCANB * 4);
    int* bofs = (int*)alloc((size_t)NREL * SCANB * 4);

    hipMemsetAsync(deg, 0, (size_t)NREL * NNODES * 4, stream);
    cast_bf16_kernel<<<12500, 256, 0, stream>>>(x, xB, (long)NNODES * INF);
    prep_weights_kernel<<<1920, 256, 0, stream>>>(Wself1, Wneigh1, Wself2, Wneigh2,
                                                  b1, b2, WT1, WT2, b1s, b2s);
    hist_kernel<<<dim3(977, 4), 256, 0, stream>>>(edst, deg);
    scan1_kernel<<<NREL * SCANB, 1024, 0, stream>>>(deg, rp, bsum);
    scan2_kernel<<<1, 256, 0, stream>>>(bsum, bofs);
    scan3_kernel<<<NREL * SCANB, 1024, 0, stream>>>(rp, cur, bofs);
    fill_kernel<<<dim3(977, 4), 256, 0, stream>>>(esrc, edst, cur, col);

    // layer 1
    aggregate_kernel<<<dim3(12500, 4), 256, 0, stream>>>(xB, rp, col, mB);
    gemm_kernel<HIDF, 0><<<dim3(4, 391), 256, 0, stream>>>(
        xB, mB, mB + plane, mB + 2 * plane, mB + 3 * plane, WT1, b1s, h1B, NNODES);

    // layer 2
    aggregate_kernel<<<dim3(12500, 4), 256, 0, stream>>>(h1B, rp, col, mB);
    gemm_kernel<OUTF, 1><<<dim3(2, 391), 256, 0, stream>>>(
        h1B, mB, mB + plane, mB + 2 * plane, mB + 3 * plane, WT2, b2s, d_out, NNODES);
}

// Round 6
// 843.448 us; speedup vs baseline: 1.0285x; 1.0285x over previous
//
#include <hip/hip_runtime.h>
#include <stdint.h>

#define NNODES 50000
#define NREL 4
#define NEDGES 250000
#define INF 512
#define HIDF 512
#define OUTF 256
#define KCAT 2560   // 5 * 512
#define SCANB 49    // ceil(50000/1024)

typedef unsigned short u16;
typedef u16 u16x8 __attribute__((ext_vector_type(8)));
typedef __bf16 bf16x8 __attribute__((ext_vector_type(8)));
typedef float f32x4 __attribute__((ext_vector_type(4)));

__device__ __forceinline__ float bf2f(u16 b) {
    unsigned u = ((unsigned)b) << 16;
    return __builtin_bit_cast(float, u);
}
__device__ __forceinline__ u16 f2bf(float f) {
    unsigned u = __builtin_bit_cast(unsigned, f);
    u = (u + 0x7fffu + ((u >> 16) & 1u)) >> 16;
    return (u16)u;
}

#define GLOAD_LDS16(gsrc, ldst)                                                  \
    __builtin_amdgcn_global_load_lds(                                            \
        (__attribute__((address_space(1))) void*)(gsrc),                         \
        (__attribute__((address_space(3))) void*)(ldst), 16, 0, 0)

// ---------------- setup kernels ----------------

__global__ void cast_bf16_kernel(const float* __restrict__ in, u16* __restrict__ out, long total) {
    long i = ((long)blockIdx.x * blockDim.x + threadIdx.x) * 8;
    long stride = (long)gridDim.x * blockDim.x * 8;
    for (; i + 7 < total; i += stride) {
        float4 v0 = *(const float4*)(in + i);
        float4 v1 = *(const float4*)(in + i + 4);
        u16x8 o;
        o[0] = f2bf(v0.x); o[1] = f2bf(v0.y); o[2] = f2bf(v0.z); o[3] = f2bf(v0.w);
        o[4] = f2bf(v1.x); o[5] = f2bf(v1.y); o[6] = f2bf(v1.z); o[7] = f2bf(v1.w);
        *(u16x8*)(out + i) = o;
    }
}

// Coalesced weight transpose via 64x64 LDS tile (+1 pad).
// WT[n][s*512 + k]; s=0 -> sum_r Wself[r][k][n]; s=1..4 -> Wneigh[s-1][k][n]
// Source reads coalesced along n; dest writes coalesced along k.
__global__ __launch_bounds__(256) void prep_w_kernel(
    const float* __restrict__ Ws1, const float* __restrict__ Wn1,
    const float* __restrict__ Ws2, const float* __restrict__ Wn2,
    u16* __restrict__ WT1, u16* __restrict__ WT2) {
    __shared__ float tile[64][65];
    int bid = blockIdx.x;
    const float* Wself; const float* Wneigh; u16* WT;
    int N, s, kt, nt;
    if (bid < 320) {                 // WT1: 5 slots x 8 ktiles x 8 ntiles
        N = HIDF; WT = WT1; Wself = Ws1; Wneigh = Wn1;
        s = bid >> 6; int r = bid & 63; kt = r >> 3; nt = r & 7;
    } else {                         // WT2: 5 slots x 8 ktiles x 4 ntiles
        int b = bid - 320;
        N = OUTF; WT = WT2; Wself = Ws2; Wneigh = Wn2;
        s = b >> 5; int r = b & 31; kt = r >> 2; nt = r & 3;
    }
    int l = threadIdx.x & 63, wv = threadIdx.x >> 6;
    int n0 = nt * 64 + l;
    // load 64 k-rows, coalesced along n
    for (int i = 0; i < 16; ++i) {
        int kl = wv + i * 4;
        int k = kt * 64 + kl;
        float v;
        if (s == 0) {
            v = Wself[(size_t)k * N + n0] + Wself[((size_t)512 + k) * N + n0] +
                Wself[((size_t)1024 + k) * N + n0] + Wself[((size_t)1536 + k) * N + n0];
        } else {
            v = Wneigh[((size_t)(s - 1) * 512 + k) * N + n0];
        }
        tile[kl][l] = v;
    }
    __syncthreads();
    // write 64 n-rows, coalesced along k
    for (int i = 0; i < 16; ++i) {
        int nl = wv + i * 4;
        WT[(size_t)(nt * 64 + nl) * KCAT + s * 512 + kt * 64 + l] = f2bf(tile[l][nl]);
    }
}

__global__ void prep_bias_kernel(const float* __restrict__ b1, const float* __restrict__ b2,
                                 float* __restrict__ b1s, float* __restrict__ b2s) {
    int t = threadIdx.x;
    if (t < HIDF) b1s[t] = b1[t] + b1[HIDF + t] + b1[2 * HIDF + t] + b1[3 * HIDF + t];
    if (t < OUTF) b2s[t] = b2[t] + b2[OUTF + t] + b2[2 * OUTF + t] + b2[3 * OUTF + t];
}

// ---------------- CSR build ----------------

__global__ void hist_kernel(const int* __restrict__ dst, int* __restrict__ deg) {
    int r = blockIdx.y;
    int i = blockIdx.x * blockDim.x + threadIdx.x;
    if (i < NEDGES) atomicAdd(&deg[r * NNODES + dst[r * NEDGES + i]], 1);
}

// 3-kernel scan: per-block exclusive scan + block sums -> scan block sums -> add offsets
__global__ __launch_bounds__(1024) void scan1_kernel(const int* __restrict__ deg,
                                                     int* __restrict__ rp, int* __restrict__ bsum) {
    int rel = blockIdx.x / SCANB, blk = blockIdx.x % SCANB;
    int i = blk * 1024 + threadIdx.x;
    int v = (i < NNODES) ? deg[rel * NNODES + i] : 0;
    __shared__ int wsum[16];
    int lane = threadIdx.x & 63, wid = threadIdx.x >> 6;
    int x = v;
#pragma unroll
    for (int off = 1; off < 64; off <<= 1) {
        int o = __shfl_up(x, off);
        if (lane >= off) x += o;
    }
    if (lane == 63) wsum[wid] = x;
    __syncthreads();
    if (wid == 0) {
        int s = (lane < 16) ? wsum[lane] : 0;
#pragma unroll
        for (int off = 1; off < 16; off <<= 1) {
            int o = __shfl_up(s, off);
            if (lane >= off) s += o;
        }
        if (lane < 16) wsum[lane] = s;
    }
    __syncthreads();
    int excl = (wid > 0 ? wsum[wid - 1] : 0) + x - v;
    if (i < NNODES) rp[rel * (NNODES + 1) + i] = excl;
    if (threadIdx.x == 1023) bsum[blockIdx.x] = excl + v;
}

__global__ void scan2_kernel(const int* __restrict__ bsum, int* __restrict__ bofs) {
    int r = threadIdx.x >> 6, lane = threadIdx.x & 63;  // 4 waves, one per rel
    int v = (lane < SCANB) ? bsum[r * SCANB + lane] : 0;
    int x = v;
#pragma unroll
    for (int off = 1; off < 64; off <<= 1) {
        int o = __shfl_up(x, off);
        if (lane >= off) x += o;
    }
    if (lane < SCANB) bofs[r * SCANB + lane] = x - v;
}

__global__ __launch_bounds__(1024) void scan3_kernel(int* __restrict__ rp, int* __restrict__ cur,
                                                     const int* __restrict__ bofs) {
    int rel = blockIdx.x / SCANB, blk = blockIdx.x % SCANB;
    int i = blk * 1024 + threadIdx.x;
    if (i < NNODES) {
        int v = rp[rel * (NNODES + 1) + i] + bofs[rel * SCANB + blk];
        rp[rel * (NNODES + 1) + i] = v;
        cur[rel * NNODES + i] = v;
        if (i == 0) rp[rel * (NNODES + 1) + NNODES] = NEDGES;
    }
}

__global__ void fill_kernel(const int* __restrict__ esrc, const int* __restrict__ edst,
                            int* __restrict__ cur, int* __restrict__ col) {
    int r = blockIdx.y;
    int i = blockIdx.x * blockDim.x + threadIdx.x;
    if (i < NEDGES) {
        int d = edst[r * NEDGES + i];
        int pos = atomicAdd(&cur[r * NNODES + d], 1);
        col[r * NEDGES + pos] = esrc[r * NEDGES + i];
    }
}

// ---------------- aggregation: one wave per (node, rel) ----------------
// out[rel][node][f] = (sum_{e} src[col[e]][f]) / max(deg,1), bf16
// masked-8 round: always issue 8 independent 1KB row loads (index clamped, weight 0
// for e>=lim, 1/deg folded into weight) -> deg<=8 nodes (93%) finish in ONE
// latency round with no serial tail.

__global__ __launch_bounds__(256) void aggregate_kernel(const u16* __restrict__ src,
                                                        const int* __restrict__ rp,
                                                        const int* __restrict__ col,
                                                        u16* __restrict__ out) {
    int node = blockIdx.x * 4 + (threadIdx.x >> 6);
    int rel = blockIdx.y;
    if (node >= NNODES) return;
    const int* r = rp + rel * (NNODES + 1);
    const int* cl = col + rel * NEDGES;
    int l = threadIdx.x & 63;
    int p0 = r[node], p1 = r[node + 1];
    int d = p1 - p0;
    float scale = (d > 0) ? 1.0f / (float)d : 1.0f;
    float acc[8] = {0.f, 0.f, 0.f, 0.f, 0.f, 0.f, 0.f, 0.f};
    const u16* srcl = src + l * 8;
    for (int base = 0; base < d; base += 64) {
        int ci = p0 + base + l;
        int myc = cl[ci < p1 ? ci : (p1 - 1)];   // coalesced index block for this wave
        int lim = d - base;
        if (lim > 64) lim = 64;
        for (int e = 0; e < lim; e += 8) {
            int idx[8]; float wgt[8];
#pragma unroll
            for (int j = 0; j < 8; ++j) {
                int ee = e + j;
                int lane = (ee < lim) ? ee : e;          // wave-uniform
                idx[j] = __builtin_amdgcn_readlane(myc, lane);
                wgt[j] = (ee < lim) ? scale : 0.0f;
            }
            u16x8 v[8];
#pragma unroll
            for (int j = 0; j < 8; ++j) v[j] = *(const u16x8*)(srcl + (size_t)idx[j] * 512);
#pragma unroll
            for (int j = 0; j < 8; ++j)
#pragma unroll
                for (int f = 0; f < 8; ++f) acc[f] += wgt[j] * bf2f(v[j][f]);
        }
    }
    u16x8 o;
#pragma unroll
    for (int j = 0; j < 8; ++j) o[j] = f2bf(acc[j]);
    *(u16x8*)(out + ((size_t)rel * NNODES + node) * 512 + l * 8) = o;
}

// ---------------- GEMM: C[M][N] = concat_K(A0..A4) @ WT^T + bias ----------------
// (unchanged control: 128x128 m97-structure + XCD-bijective swizzle; verified
//  FETCH ~156MB, MfmaUtil ~33%, 0 bank conflicts)

template <int N, int OUTMODE>
__global__ __launch_bounds__(256, 4) void gemm_kernel(
    const u16* __restrict__ A0, const u16* __restrict__ A1, const u16* __restrict__ A2,
    const u16* __restrict__ A3, const u16* __restrict__ A4, const u16* __restrict__ WT,
    const float* __restrict__ bias, void* __restrict__ outp, int M) {
    __shared__ u16 ldsA[128 * 64];
    __shared__ u16 ldsB[128 * 64];
    const int t = threadIdx.x;
    const int w = t >> 6, l = t & 63;
    const int wr = w >> 1, wc = w & 1;

    constexpr int ncol = N >> 7;
    const int nwg = gridDim.x * gridDim.y;
    const int orig = blockIdx.y * gridDim.x + blockIdx.x;  // hardware dispatch order
    const int q = nwg >> 3, rr = nwg & 7, xcd = orig & 7, loc = orig >> 3;
    const int v = (xcd < rr) ? xcd * (q + 1) + loc : rr * (q + 1) + (xcd - rr) * q + loc;
    const int rowBase = (v / ncol) * 128;
    const int colBase = (v % ncol) * 128;

    f32x4 acc[4][4] = {};

    const u16* const As[5] = {A0, A1, A2, A3, A4};
    const int sr = t >> 3;       // 0..31 staging row within a call
    const int gp = t & 7;        // physical granule (16B)
    const int lr = l & 15, lg = l >> 4;

#pragma unroll
    for (int s = 0; s < 5; ++s) {
        const u16* __restrict__ Asrc = As[s];
        for (int ts = 0; ts < 8; ++ts) {
            const int klocal = ts * 64;
            const int kglob = s * 512 + klocal;
#pragma unroll
            for (int c = 0; c < 4; ++c) {
                int r = c * 32 + sr;
                int gl = gp ^ (r & 7);
                int grow = rowBase + r;
                if (grow > M - 1) grow = M - 1;
                const u16* gsrc = Asrc + (size_t)grow * 512 + klocal + gl * 8;
                GLOAD_LDS16(gsrc, ldsA + (c * 2048 + w * 512));
            }
#pragma unroll
            for (int c = 0; c < 4; ++c) {
                int r = c * 32 + sr;
                int gl = gp ^ (r & 7);
                const u16* gsrc = WT + (size_t)(colBase + r) * KCAT + kglob + gl * 8;
                GLOAD_LDS16(gsrc, ldsB + (c * 2048 + w * 512));
            }
            __syncthreads();
#pragma unroll
            for (int kh = 0; kh < 2; ++kh) {
                bf16x8 av[4], bv[4];
#pragma unroll
                for (int m = 0; m < 4; ++m) {
                    int r = wr * 64 + m * 16 + lr;
                    int g = (kh * 4 + lg) ^ (r & 7);
                    av[m] = *(const bf16x8*)((const char*)ldsA + r * 128 + g * 16);
                }
#pragma unroll
                for (int n = 0; n < 4; ++n) {
                    int r = wc * 64 + n * 16 + lr;
                    int g = (kh * 4 + lg) ^ (r & 7);
                    bv[n] = *(const bf16x8*)((const char*)ldsB + r * 128 + g * 16);
                }
#pragma unroll
                for (int m = 0; m < 4; ++m)
#pragma unroll
                    for (int n = 0; n < 4; ++n)
                        acc[m][n] =
                            __builtin_amdgcn_mfma_f32_16x16x32_bf16(av[m], bv[n], acc[m][n], 0, 0, 0);
            }
            __syncthreads();
        }
    }

    const int lq = l >> 4;
#pragma unroll
    for (int m = 0; m < 4; ++m) {
#pragma unroll
        for (int n = 0; n < 4; ++n) {
#pragma unroll
            for (int j = 0; j < 4; ++j) {
                int row = rowBase + wr * 64 + m * 16 + lq * 4 + j;
                int colc = colBase + wc * 64 + n * 16 + lr;
                if (row < M) {
                    float vv = acc[m][n][j] + bias[colc];
                    if (OUTMODE == 0) {
                        vv = vv > 0.f ? vv : 0.f;
                        ((u16*)outp)[(size_t)row * N + colc] = f2bf(vv);
                    } else {
                        ((float*)outp)[(size_t)row * N + colc] = vv;
                    }
                }
            }
        }
    }
}

// ---------------- host ----------------

extern "C" void kernel_launch(void* const* d_in, const int* in_sizes, int n_in,
                              void* d_out, int out_size, void* d_ws, size_t ws_size,
                              hipStream_t stream) {
    const float* x = (const float*)d_in[0];
    const float* Wself1 = (const float*)d_in[1];
    const float* Wneigh1 = (const float*)d_in[2];
    const float* b1 = (const float*)d_in[3];
    const float* Wself2 = (const float*)d_in[4];
    const float* Wneigh2 = (const float*)d_in[5];
    const float* b2 = (const float*)d_in[6];
    const int* esrc = (const int*)d_in[7];
    const int* edst = (const int*)d_in[8];

    char* ws = (char*)d_ws;
    size_t off = 0;
    auto alloc = [&](size_t bytes) {
        char* p = ws + off;
        off += (bytes + 255) & ~(size_t)255;
        return p;
    };
    const size_t plane = (size_t)NNODES * 512;
    u16* xB = (u16*)alloc(plane * 2);             // x in bf16
    u16* mB = (u16*)alloc(NREL * plane * 2);      // 4 aggregate buffers
    u16* h1B = (u16*)alloc(plane * 2);            // relu(h1) in bf16
    u16* WT1 = (u16*)alloc((size_t)HIDF * KCAT * 2);
    u16* WT2 = (u16*)alloc((size_t)OUTF * KCAT * 2);
    float* b1s = (float*)alloc(HIDF * 4);
    float* b2s = (float*)alloc(OUTF * 4);
    int* deg = (int*)alloc((size_t)NREL * NNODES * 4);
    int* rp = (int*)alloc((size_t)NREL * (NNODES + 1) * 4);
    int* cur = (int*)alloc((size_t)NREL * NNODES * 4);
    int* col = (int*)alloc((size_t)NREL * NEDGES * 4);
    int* bsum = (int*)alloc((size_t)NREL * SCANB * 4);
    int* bofs = (int*)alloc((size_t)NREL * SCANB * 4);

    hipMemsetAsync(deg, 0, (size_t)NREL * NNODES * 4, stream);
    cast_bf16_kernel<<<12500, 256, 0, stream>>>(x, xB, (long)NNODES * INF);
    prep_w_kernel<<<480, 256, 0, stream>>>(Wself1, Wneigh1, Wself2, Wneigh2, WT1, WT2);
    prep_bias_kernel<<<1, 512, 0, stream>>>(b1, b2, b1s, b2s);
    hist_kernel<<<dim3(977, 4), 256, 0, stream>>>(edst, deg);
    scan1_kernel<<<NREL * SCANB, 1024, 0, stream>>>(deg, rp, bsum);
    scan2_kernel<<<1, 256, 0, stream>>>(bsum, bofs);
    scan3_kernel<<<NREL * SCANB, 1024, 0, stream>>>(rp, cur, bofs);
    fill_kernel<<<dim3(977, 4), 256, 0, stream>>>(esrc, edst, cur, col);

    // layer 1
    aggregate_kernel<<<dim3(12500, 4), 256, 0, stream>>>(xB, rp, col, mB);
    gemm_kernel<HIDF, 0><<<dim3(4, 391), 256, 0, stream>>>(
        xB, mB, mB + plane, mB + 2 * plane, mB + 3 * plane, WT1, b1s, h1B, NNODES);

    // layer 2
    aggregate_kernel<<<dim3(12500, 4), 256, 0, stream>>>(h1B, rp, col, mB);
    gemm_kernel<OUTF, 1><<<dim3(2, 391), 256, 0, stream>>>(
        h1B, mB, mB + plane, mB + 2 * plane, mB + 3 * plane, WT2, b2s, d_out, NNODES);
}

// Round 7
// 795.868 us; speedup vs baseline: 1.0900x; 1.0598x over previous
//
#include <hip/hip_runtime.h>
#include <stdint.h>

#define NNODES 50000
#define NREL 4
#define INF 512
#define HIDF 512
#define OUTF 256
#define NEDGES 250000
#define KCAT 2560   // 5 * 512 (layer-1 concat K)
#define N2 1280     // layer-2' output width: 256 self + 4*256 neigh planes
#define SCANB 49    // ceil(50000/1024)

typedef unsigned short u16;
typedef u16 u16x4 __attribute__((ext_vector_type(4)));
typedef u16 u16x8 __attribute__((ext_vector_type(8)));
typedef __bf16 bf16x8 __attribute__((ext_vector_type(8)));
typedef float f32x4 __attribute__((ext_vector_type(4)));

__device__ __forceinline__ float bf2f(u16 b) {
    unsigned u = ((unsigned)b) << 16;
    return __builtin_bit_cast(float, u);
}
__device__ __forceinline__ u16 f2bf(float f) {
    unsigned u = __builtin_bit_cast(unsigned, f);
    u = (u + 0x7fffu + ((u >> 16) & 1u)) >> 16;
    return (u16)u;
}

#define GLOAD_LDS16(gsrc, ldst)                                                  \
    __builtin_amdgcn_global_load_lds(                                            \
        (__attribute__((address_space(1))) void*)(gsrc),                         \
        (__attribute__((address_space(3))) void*)(ldst), 16, 0, 0)

// ---------------- setup kernels ----------------

__global__ void cast_bf16_kernel(const float* __restrict__ in, u16* __restrict__ out, long total) {
    long i = ((long)blockIdx.x * blockDim.x + threadIdx.x) * 8;
    long stride = (long)gridDim.x * blockDim.x * 8;
    for (; i + 7 < total; i += stride) {
        float4 v0 = *(const float4*)(in + i);
        float4 v1 = *(const float4*)(in + i + 4);
        u16x8 o;
        o[0] = f2bf(v0.x); o[1] = f2bf(v0.y); o[2] = f2bf(v0.z); o[3] = f2bf(v0.w);
        o[4] = f2bf(v1.x); o[5] = f2bf(v1.y); o[6] = f2bf(v1.z); o[7] = f2bf(v1.w);
        *(u16x8*)(out + i) = o;
    }
}

// Coalesced weight transpose via 64x64 LDS tile (+1 pad).
// WT1[n][s*512+k], n<512: s=0 -> sum_r Wself1[r][k][n]; s=1..4 -> Wneigh1[s-1][k][n]
// WT2[n][k], n<1280:  n<256 -> sum_r Wself2[r][k][n]; else plane s=n>>8 -> Wneigh2[s-1][k][n&255]
__global__ __launch_bounds__(256) void prep_w_kernel(
    const float* __restrict__ Ws1, const float* __restrict__ Wn1,
    const float* __restrict__ Ws2, const float* __restrict__ Wn2,
    u16* __restrict__ WT1, u16* __restrict__ WT2) {
    __shared__ float tile[64][65];
    int bid = blockIdx.x;
    int l = threadIdx.x & 63, wv = threadIdx.x >> 6;
    if (bid < 320) {                 // WT1: 5 slots x 8 ktiles x 8 ntiles
        int s = bid >> 6, r = bid & 63, kt = r >> 3, nt = r & 7;
        int n0 = nt * 64 + l;
        for (int i = 0; i < 16; ++i) {
            int kl = wv + i * 4;
            int k = kt * 64 + kl;
            float v;
            if (s == 0) {
                v = Ws1[(size_t)k * HIDF + n0] + Ws1[((size_t)512 + k) * HIDF + n0] +
                    Ws1[((size_t)1024 + k) * HIDF + n0] + Ws1[((size_t)1536 + k) * HIDF + n0];
            } else {
                v = Wn1[((size_t)(s - 1) * 512 + k) * HIDF + n0];
            }
            tile[kl][l] = v;
        }
        __syncthreads();
        for (int i = 0; i < 16; ++i) {
            int nl = wv + i * 4;
            WT1[(size_t)(nt * 64 + nl) * KCAT + s * 512 + kt * 64 + l] = f2bf(tile[l][nl]);
        }
    } else {                         // WT2: [1280][512] = 20 ntiles x 8 ktiles
        int b = bid - 320;
        int nt = b >> 3, kt = b & 7;
        int n0 = nt * 64 + l;
        int s = n0 >> 8, nn = n0 & 255;
        for (int i = 0; i < 16; ++i) {
            int kl = wv + i * 4;
            int k = kt * 64 + kl;
            float v;
            if (s == 0) {
                v = Ws2[(size_t)k * OUTF + nn] + Ws2[((size_t)512 + k) * OUTF + nn] +
                    Ws2[((size_t)1024 + k) * OUTF + nn] + Ws2[((size_t)1536 + k) * OUTF + nn];
            } else {
                v = Wn2[((size_t)(s - 1) * 512 + k) * OUTF + nn];
            }
            tile[kl][l] = v;
        }
        __syncthreads();
        for (int i = 0; i < 16; ++i) {
            int nl = wv + i * 4;
            WT2[(size_t)(nt * 64 + nl) * 512 + kt * 64 + l] = f2bf(tile[l][nl]);
        }
    }
}

// b1s[512] = sum_r b1[r]; b2e[1280] = sum_r b2[r] for cols<256, 0 elsewhere
__global__ void prep_bias_kernel(const float* __restrict__ b1, const float* __restrict__ b2,
                                 float* __restrict__ b1s, float* __restrict__ b2e) {
    int t = blockIdx.x * 1024 + threadIdx.x;
    if (t < HIDF) b1s[t] = b1[t] + b1[HIDF + t] + b1[2 * HIDF + t] + b1[3 * HIDF + t];
    int i = t - 512;
    if (i >= 0 && i < N2)
        b2e[i] = (i < OUTF) ? (b2[i] + b2[OUTF + i] + b2[2 * OUTF + i] + b2[3 * OUTF + i]) : 0.f;
}

// ---------------- CSR build ----------------

__global__ void hist_kernel(const int* __restrict__ dst, int* __restrict__ deg) {
    int r = blockIdx.y;
    int i = blockIdx.x * blockDim.x + threadIdx.x;
    if (i < NEDGES) atomicAdd(&deg[r * NNODES + dst[r * NEDGES + i]], 1);
}

__global__ __launch_bounds__(1024) void scan1_kernel(const int* __restrict__ deg,
                                                     int* __restrict__ rp, int* __restrict__ bsum) {
    int rel = blockIdx.x / SCANB, blk = blockIdx.x % SCANB;
    int i = blk * 1024 + threadIdx.x;
    int v = (i < NNODES) ? deg[rel * NNODES + i] : 0;
    __shared__ int wsum[16];
    int lane = threadIdx.x & 63, wid = threadIdx.x >> 6;
    int x = v;
#pragma unroll
    for (int off = 1; off < 64; off <<= 1) {
        int o = __shfl_up(x, off);
        if (lane >= off) x += o;
    }
    if (lane == 63) wsum[wid] = x;
    __syncthreads();
    if (wid == 0) {
        int s = (lane < 16) ? wsum[lane] : 0;
#pragma unroll
        for (int off = 1; off < 16; off <<= 1) {
            int o = __shfl_up(s, off);
            if (lane >= off) s += o;
        }
        if (lane < 16) wsum[lane] = s;
    }
    __syncthreads();
    int excl = (wid > 0 ? wsum[wid - 1] : 0) + x - v;
    if (i < NNODES) rp[rel * (NNODES + 1) + i] = excl;
    if (threadIdx.x == 1023) bsum[blockIdx.x] = excl + v;
}

__global__ void scan2_kernel(const int* __restrict__ bsum, int* __restrict__ bofs) {
    int r = threadIdx.x >> 6, lane = threadIdx.x & 63;
    int v = (lane < SCANB) ? bsum[r * SCANB + lane] : 0;
    int x = v;
#pragma unroll
    for (int off = 1; off < 64; off <<= 1) {
        int o = __shfl_up(x, off);
        if (lane >= off) x += o;
    }
    if (lane < SCANB) bofs[r * SCANB + lane] = x - v;
}

__global__ __launch_bounds__(1024) void scan3_kernel(int* __restrict__ rp, int* __restrict__ cur,
                                                     const int* __restrict__ bofs) {
    int rel = blockIdx.x / SCANB, blk = blockIdx.x % SCANB;
    int i = blk * 1024 + threadIdx.x;
    if (i < NNODES) {
        int v = rp[rel * (NNODES + 1) + i] + bofs[rel * SCANB + blk];
        rp[rel * (NNODES + 1) + i] = v;
        cur[rel * NNODES + i] = v;
        if (i == 0) rp[rel * (NNODES + 1) + NNODES] = NEDGES;
    }
}

__global__ void fill_kernel(const int* __restrict__ esrc, const int* __restrict__ edst,
                            int* __restrict__ cur, int* __restrict__ col) {
    int r = blockIdx.y;
    int i = blockIdx.x * blockDim.x + threadIdx.x;
    if (i < NEDGES) {
        int d = edst[r * NEDGES + i];
        int pos = atomicAdd(&cur[r * NNODES + d], 1);
        col[r * NEDGES + pos] = esrc[r * NEDGES + i];
    }
}

// ---------------- layer-1 aggregation: one wave per (node, rel) ----------------
// masked-8 round over 1KB bf16 rows of src (dup loads L1-absorbed).

__global__ __launch_bounds__(256) void aggregate_kernel(const u16* __restrict__ src,
                                                        const int* __restrict__ rp,
                                                        const int* __restrict__ col,
                                                        u16* __restrict__ out) {
    int node = blockIdx.x * 4 + (threadIdx.x >> 6);
    int rel = blockIdx.y;
    if (node >= NNODES) return;
    const int* r = rp + rel * (NNODES + 1);
    const int* cl = col + rel * NEDGES;
    int l = threadIdx.x & 63;
    int p0 = r[node], p1 = r[node + 1];
    int d = p1 - p0;
    float scale = (d > 0) ? 1.0f / (float)d : 1.0f;
    float acc[8] = {0.f, 0.f, 0.f, 0.f, 0.f, 0.f, 0.f, 0.f};
    const u16* srcl = src + l * 8;
    for (int base = 0; base < d; base += 64) {
        int ci = p0 + base + l;
        int myc = cl[ci < p1 ? ci : (p1 - 1)];
        int lim = d - base;
        if (lim > 64) lim = 64;
        for (int e = 0; e < lim; e += 8) {
            int idx[8]; float wgt[8];
#pragma unroll
            for (int j = 0; j < 8; ++j) {
                int ee = e + j;
                int lane = (ee < lim) ? ee : e;
                idx[j] = __builtin_amdgcn_readlane(myc, lane);
                wgt[j] = (ee < lim) ? scale : 0.0f;
            }
            u16x8 v[8];
#pragma unroll
            for (int j = 0; j < 8; ++j) v[j] = *(const u16x8*)(srcl + (size_t)idx[j] * 512);
#pragma unroll
            for (int j = 0; j < 8; ++j)
#pragma unroll
                for (int f = 0; f < 8; ++f) acc[f] += wgt[j] * bf2f(v[j][f]);
        }
    }
    u16x8 o;
#pragma unroll
    for (int j = 0; j < 8; ++j) o[j] = f2bf(acc[j]);
    *(u16x8*)(out + ((size_t)rel * NNODES + node) * 512 + l * 8) = o;
}

// ---------------- layer-2 aggregation in PROJECTION space ----------------
// P[node][1280] bf16: cols [0,256) = h1@Wself2s + b2 (self part);
// cols [256+r*256, 256+(r+1)*256) = (h1@Wneigh2_r)[node].
// out[node][f] = P[node][f] + sum_r mean_{e in CSR_r[node]} P[src_e][256+r*256+f], f32.
// Gathered rows are 512B (half of layer-1) -> halves the L2/L3 gather traffic.

__global__ __launch_bounds__(256) void aggregate2_kernel(const u16* __restrict__ P,
                                                         const int* __restrict__ rp,
                                                         const int* __restrict__ col,
                                                         float* __restrict__ out) {
    int node = blockIdx.x * 4 + (threadIdx.x >> 6);
    if (node >= NNODES) return;
    int l = threadIdx.x & 63;
    u16x4 sv = *(const u16x4*)(P + (size_t)node * N2 + l * 4);
    float a0 = bf2f(sv[0]), a1 = bf2f(sv[1]), a2 = bf2f(sv[2]), a3 = bf2f(sv[3]);
#pragma unroll
    for (int r = 0; r < NREL; ++r) {
        const int* rpn = rp + r * (NNODES + 1);
        const int* cl = col + r * NEDGES;
        int p0 = rpn[node], p1 = rpn[node + 1];
        int d = p1 - p0;
        if (d <= 0) continue;
        float scale = 1.0f / (float)d;
        const u16* base = P + 256 + r * 256 + (size_t)l * 4;
        for (int b = 0; b < d; b += 64) {
            int ci = p0 + b + l;
            int myc = cl[ci < p1 ? ci : (p1 - 1)];
            int lim = d - b;
            if (lim > 64) lim = 64;
            for (int e = 0; e < lim; e += 8) {
                int idx[8]; float wgt[8];
#pragma unroll
                for (int j = 0; j < 8; ++j) {
                    int ee = e + j;
                    idx[j] = __builtin_amdgcn_readlane(myc, (ee < lim) ? ee : e);
                    wgt[j] = (ee < lim) ? scale : 0.0f;
                }
                u16x4 v[8];
#pragma unroll
                for (int j = 0; j < 8; ++j)
                    v[j] = *(const u16x4*)(base + (size_t)idx[j] * N2);
#pragma unroll
                for (int j = 0; j < 8; ++j) {
                    a0 += wgt[j] * bf2f(v[j][0]);
                    a1 += wgt[j] * bf2f(v[j][1]);
                    a2 += wgt[j] * bf2f(v[j][2]);
                    a3 += wgt[j] * bf2f(v[j][3]);
                }
            }
        }
    }
    float4 o = {a0, a1, a2, a3};
    *(float4*)(out + (size_t)node * OUTF + l * 4) = o;
}

// ---------------- GEMM: C[M][N] = concat_K(A0..A{NPL-1}) @ WT^T + bias ----------------
// WT: [N][NPL*512] bf16 row-major. OUTMODE 0: bf16(relu(acc+bias)); 2: bf16(acc+bias).
// XCD-bijective dispatch swizzle (m204): col-blocks of one row panel adjacent + same XCD.

template <int N, int NPL, int OUTMODE>
__global__ __launch_bounds__(256, 4) void gemm_kernel(
    const u16* __restrict__ A0, const u16* __restrict__ A1, const u16* __restrict__ A2,
    const u16* __restrict__ A3, const u16* __restrict__ A4, const u16* __restrict__ WT,
    const float* __restrict__ bias, void* __restrict__ outp, int M) {
    __shared__ u16 ldsA[128 * 64];
    __shared__ u16 ldsB[128 * 64];
    const int t = threadIdx.x;
    const int w = t >> 6, l = t & 63;
    const int wr = w >> 1, wc = w & 1;
    constexpr int KTOT = NPL * 512;

    constexpr int ncol = N >> 7;
    const int nwg = gridDim.x * gridDim.y;
    const int orig = blockIdx.y * gridDim.x + blockIdx.x;
    const int q = nwg >> 3, rr = nwg & 7, xcd = orig & 7, loc = orig >> 3;
    const int v = (xcd < rr) ? xcd * (q + 1) + loc : rr * (q + 1) + (xcd - rr) * q + loc;
    const int rowBase = (v / ncol) * 128;
    const int colBase = (v % ncol) * 128;

    f32x4 acc[4][4] = {};

    const u16* const As[5] = {A0, A1, A2, A3, A4};
    const int sr = t >> 3;
    const int gp = t & 7;
    const int lr = l & 15, lg = l >> 4;

#pragma unroll
    for (int s = 0; s < NPL; ++s) {
        const u16* __restrict__ Asrc = As[s];
        for (int ts = 0; ts < 8; ++ts) {
            const int klocal = ts * 64;
            const int kglob = s * 512 + klocal;
#pragma unroll
            for (int c = 0; c < 4; ++c) {
                int r = c * 32 + sr;
                int gl = gp ^ (r & 7);
                int grow = rowBase + r;
                if (grow > M - 1) grow = M - 1;
                const u16* gsrc = Asrc + (size_t)grow * 512 + klocal + gl * 8;
                GLOAD_LDS16(gsrc, ldsA + (c * 2048 + w * 512));
            }
#pragma unroll
            for (int c = 0; c < 4; ++c) {
                int r = c * 32 + sr;
                int gl = gp ^ (r & 7);
                const u16* gsrc = WT + (size_t)(colBase + r) * KTOT + kglob + gl * 8;
                GLOAD_LDS16(gsrc, ldsB + (c * 2048 + w * 512));
            }
            __syncthreads();
#pragma unroll
            for (int kh = 0; kh < 2; ++kh) {
                bf16x8 av[4], bv[4];
#pragma unroll
                for (int m = 0; m < 4; ++m) {
                    int r = wr * 64 + m * 16 + lr;
                    int g = (kh * 4 + lg) ^ (r & 7);
                    av[m] = *(const bf16x8*)((const char*)ldsA + r * 128 + g * 16);
                }
#pragma unroll
                for (int n = 0; n < 4; ++n) {
                    int r = wc * 64 + n * 16 + lr;
                    int g = (kh * 4 + lg) ^ (r & 7);
                    bv[n] = *(const bf16x8*)((const char*)ldsB + r * 128 + g * 16);
                }
#pragma unroll
                for (int m = 0; m < 4; ++m)
#pragma unroll
                    for (int n = 0; n < 4; ++n)
                        acc[m][n] =
                            __builtin_amdgcn_mfma_f32_16x16x32_bf16(av[m], bv[n], acc[m][n], 0, 0, 0);
            }
            __syncthreads();
        }
    }

    const int lq = l >> 4;
#pragma unroll
    for (int m = 0; m < 4; ++m) {
#pragma unroll
        for (int n = 0; n < 4; ++n) {
#pragma unroll
            for (int j = 0; j < 4; ++j) {
                int row = rowBase + wr * 64 + m * 16 + lq * 4 + j;
                int colc = colBase + wc * 64 + n * 16 + lr;
                if (row < M) {
                    float vv = acc[m][n][j] + bias[colc];
                    if (OUTMODE == 0) vv = vv > 0.f ? vv : 0.f;
                    ((u16*)outp)[(size_t)row * N + colc] = f2bf(vv);
                }
            }
        }
    }
}

// ---------------- host ----------------

extern "C" void kernel_launch(void* const* d_in, const int* in_sizes, int n_in,
                              void* d_out, int out_size, void* d_ws, size_t ws_size,
                              hipStream_t stream) {
    const float* x = (const float*)d_in[0];
    const float* Wself1 = (const float*)d_in[1];
    const float* Wneigh1 = (const float*)d_in[2];
    const float* b1 = (const float*)d_in[3];
    const float* Wself2 = (const float*)d_in[4];
    const float* Wneigh2 = (const float*)d_in[5];
    const float* b2 = (const float*)d_in[6];
    const int* esrc = (const int*)d_in[7];
    const int* edst = (const int*)d_in[8];

    char* ws = (char*)d_ws;
    size_t off = 0;
    auto alloc = [&](size_t bytes) {
        char* p = ws + off;
        off += (bytes + 255) & ~(size_t)255;
        return p;
    };
    const size_t plane = (size_t)NNODES * 512;
    u16* xB = (u16*)alloc(plane * 2);             // x in bf16
    u16* mB = (u16*)alloc(NREL * plane * 2);      // L1 aggregate buffers; reused as P (50000x1280)
    u16* h1B = (u16*)alloc(plane * 2);            // relu(h1) in bf16
    u16* WT1 = (u16*)alloc((size_t)HIDF * KCAT * 2);
    u16* WT2 = (u16*)alloc((size_t)N2 * 512 * 2);
    float* b1s = (float*)alloc(HIDF * 4);
    float* b2e = (float*)alloc(N2 * 4);
    int* deg = (int*)alloc((size_t)NREL * NNODES * 4);
    int* rp = (int*)alloc((size_t)NREL * (NNODES + 1) * 4);
    int* cur = (int*)alloc((size_t)NREL * NNODES * 4);
    int* col = (int*)alloc((size_t)NREL * NEDGES * 4);
    int* bsum = (int*)alloc((size_t)NREL * SCANB * 4);
    int* bofs = (int*)alloc((size_t)NREL * SCANB * 4);

    hipMemsetAsync(deg, 0, (size_t)NREL * NNODES * 4, stream);
    cast_bf16_kernel<<<12500, 256, 0, stream>>>(x, xB, (long)NNODES * INF);
    prep_w_kernel<<<480, 256, 0, stream>>>(Wself1, Wneigh1, Wself2, Wneigh2, WT1, WT2);
    prep_bias_kernel<<<2, 1024, 0, stream>>>(b1, b2, b1s, b2e);
    hist_kernel<<<dim3(977, 4), 256, 0, stream>>>(edst, deg);
    scan1_kernel<<<NREL * SCANB, 1024, 0, stream>>>(deg, rp, bsum);
    scan2_kernel<<<1, 256, 0, stream>>>(bsum, bofs);
    scan3_kernel<<<NREL * SCANB, 1024, 0, stream>>>(rp, cur, bofs);
    fill_kernel<<<dim3(977, 4), 256, 0, stream>>>(esrc, edst, cur, col);

    // layer 1: aggregate x, then one concat-K GEMM -> relu -> h1B (bf16)
    aggregate_kernel<<<dim3(12500, 4), 256, 0, stream>>>(xB, rp, col, mB);
    gemm_kernel<HIDF, 5, 0><<<dim3(4, 391), 256, 0, stream>>>(
        xB, mB, mB + plane, mB + 2 * plane, mB + 3 * plane, WT1, b1s, h1B, NNODES);

    // layer 2: project first (P = h1 @ [Wself2s | Wn2_0..3], bf16, self plane gets bias),
    // then aggregate 512B projected rows and write f32 d_out directly.
    u16* P = mB;  // 50000 x 1280 bf16 = 128 MB, fits in mB's 205 MB
    gemm_kernel<N2, 1, 2><<<dim3(10, 391), 256, 0, stream>>>(
        h1B, h1B, h1B, h1B, h1B, WT2, b2e, P, NNODES);
    aggregate2_kernel<<<12500, 256, 0, stream>>>(P, rp, col, (float*)d_out);
}